// Round 1
// baseline (1336.775 us; speedup 1.0000x reference)
//
#include <hip/hip_runtime.h>
#include <cstdint>
#include <cstddef>

#define NROWS   32768
#define DIMD    256
#define NPROTO  64
#define NTYPES  17
#define NCOLS   1089          // 64*17 + 1
#define TAUINV  10.0f
#define NITERS  50
#define PB      8             // blocks per type
#define NSBLK   (NTYPES*PB)   // 136
#define MAXR    384
#define LOGN    10.397207708399179f   // ln(32768)
#define SELU_L  1.0507009873554805f
#define SELU_A  1.6732632423543772f

// ---- workspace byte offsets ----
#define WS_CNT     0          // int[17]
#define WS_OFF     128        // int[18]
#define WS_BAR     256        // int[2]  (counter, generation)
#define WS_COLP    512        // ull[2][17][8][64]  = 139264 B
#define WS_DUSTP   139776     // ull[2][136]        = 2176 B
#define WS_LVF     141952     // float[1089]
#define WS_LOGU    146432     // float[32768]
#define WS_SLOTOF  277504     // int[32768]
#define WS_PERM    408576     // int[32768]
#define WS_NDP     540672     // float[32768*64] = 8 MB

__device__ __forceinline__ unsigned long long packms(float m, float s) {
  return (unsigned long long)__float_as_uint(m) |
         ((unsigned long long)__float_as_uint(s) << 32);
}
__device__ __forceinline__ void unpackms(unsigned long long v, float& m, float& s) {
  m = __uint_as_float((unsigned)(v & 0xffffffffu));
  s = __uint_as_float((unsigned)(v >> 32));
}
// merge running (M,S) lse pair with (m,s); exp arg always <= 0
__device__ __forceinline__ void msmerge(float& M, float& S, float m, float s) {
  if (m > M) { S = S * __expf(M - m) + s; M = m; }
  else       { S += s * __expf(m - M); }
}

// ---------------- histogram of joint types ----------------
__global__ void k_hist(const int* __restrict__ jt, int* cnt) {
  int i = blockIdx.x * 256 + threadIdx.x;
  atomicAdd(&cnt[jt[i]], 1);
}

// ---------------- prefix over 17 counts ----------------
__global__ void k_scan(const int* __restrict__ cnt, int* off) {
  if (threadIdx.x == 0) {
    int run = 0;
    for (int t = 0; t < NTYPES; ++t) { off[t] = run; run += cnt[t]; }
    off[NTYPES] = run;
  }
}

// ---------------- deterministic per-type rank / permutation ----------------
__global__ void k_rank(const int* __restrict__ jt, const int* __restrict__ off,
                       int* slotOf, int* perm) {
  const int t = blockIdx.x;
  const int tid = threadIdx.x;           // 256
  const int lane = tid & 63, w = tid >> 6;
  __shared__ int wtot[4];
  int running = 0;
  for (int base = 0; base < NROWS; base += 256) {
    int i = base + tid;
    bool f = (jt[i] == t);
    unsigned long long mask = __ballot(f);
    int prefix = __popcll(mask & ((1ull << lane) - 1ull));
    int wcount = __popcll(mask);
    if (lane == 0) wtot[w] = wcount;
    __syncthreads();
    int woff = 0;
    for (int ww = 0; ww < 4; ++ww) woff += (ww < w) ? wtot[ww] : 0;
    int btot = wtot[0] + wtot[1] + wtot[2] + wtot[3];
    if (f) {
      int slot = off[t] + running + woff + prefix;
      slotOf[i] = slot;
      perm[slot] = i;
    }
    running += btot;
    __syncthreads();
  }
}

// ---------------- fused  h = selu(emb@W1+b1);  negdist -> permuted slots ----------------
__global__ __launch_bounds__(512, 1) void k_prep(
    const float* __restrict__ emb, const float* __restrict__ w1,
    const float* __restrict__ b1,  const float* __restrict__ proto,
    const int* __restrict__ slotOf, float* __restrict__ ndP)
{
  __shared__ float EH[64 * 260];   // emb tile, later overwritten with h tile
  __shared__ float PT[256 * 65];   // protoT[d][k]
  __shared__ float hh[64];
  const int tid = threadIdx.x;
  const int rowBase = blockIdx.x * 64;

  for (int idx = tid; idx < 64 * 256; idx += 512) {
    int r = idx >> 8, d = idx & 255;
    EH[r * 260 + d] = emb[(size_t)(rowBase + r) * 256 + d];
  }
  for (int idx = tid; idx < 64 * 256; idx += 512) {
    int k = idx >> 8, d = idx & 255;
    PT[d * 65 + k] = proto[idx];
  }
  __syncthreads();

  const int jj = tid & 63;
  const int rr = tid >> 6;   // 0..7

  float acc[8][4];
  #pragma unroll
  for (int m = 0; m < 8; ++m)
    #pragma unroll
    for (int c = 0; c < 4; ++c) acc[m][c] = 0.0f;
  float bb[4];
  #pragma unroll
  for (int c = 0; c < 4; ++c) bb[c] = b1[jj + 64 * c];

  for (int k4 = 0; k4 < 256; k4 += 4) {
    float4 ev[8];
    #pragma unroll
    for (int m = 0; m < 8; ++m)
      ev[m] = *(const float4*)&EH[(rr * 8 + m) * 260 + k4];
    #pragma unroll
    for (int kk = 0; kk < 4; ++kk) {
      float wv[4];
      #pragma unroll
      for (int c = 0; c < 4; ++c)
        wv[c] = w1[(size_t)(k4 + kk) * 256 + jj + 64 * c];
      #pragma unroll
      for (int m = 0; m < 8; ++m) {
        float e = (kk == 0) ? ev[m].x : (kk == 1) ? ev[m].y : (kk == 2) ? ev[m].z : ev[m].w;
        #pragma unroll
        for (int c = 0; c < 4; ++c) acc[m][c] += e * wv[c];
      }
    }
  }

  float hv[8][4];
  float hs[8];
  #pragma unroll
  for (int m = 0; m < 8; ++m) {
    hs[m] = 0.0f;
    #pragma unroll
    for (int c = 0; c < 4; ++c) {
      float g = acc[m][c] + bb[c];
      float h = (g > 0.0f) ? SELU_L * g : SELU_L * SELU_A * (__expf(g) - 1.0f);
      hv[m][c] = h;
      hs[m] += h * h;
    }
  }
  __syncthreads();   // all reads of emb tile complete
  #pragma unroll
  for (int m = 0; m < 8; ++m)
    #pragma unroll
    for (int c = 0; c < 4; ++c)
      EH[(rr * 8 + m) * 260 + jj + 64 * c] = hv[m][c];
  #pragma unroll
  for (int m = 0; m < 8; ++m) {
    float v = hs[m];
    for (int o = 32; o; o >>= 1) v += __shfl_xor(v, o);
    if (jj == 0) hh[rr * 8 + m] = v;
  }
  __syncthreads();

  // phase B: dist against 64 prototypes
  const int k = jj;
  float da[8];
  #pragma unroll
  for (int m = 0; m < 8; ++m) da[m] = 0.0f;
  float pp = 0.0f;
  for (int d4 = 0; d4 < 256; d4 += 4) {
    float pv[4];
    #pragma unroll
    for (int dd = 0; dd < 4; ++dd) {
      float v = PT[(d4 + dd) * 65 + k];
      pv[dd] = v; pp += v * v;
    }
    #pragma unroll
    for (int m = 0; m < 8; ++m) {
      float4 h4 = *(const float4*)&EH[(rr * 8 + m) * 260 + d4];
      da[m] += h4.x * pv[0] + h4.y * pv[1] + h4.z * pv[2] + h4.w * pv[3];
    }
  }
  #pragma unroll
  for (int m = 0; m < 8; ++m) {
    int row = rr * 8 + m;
    float dist = hh[row] + pp - 2.0f * da[m];
    dist = fmaxf(dist, 0.0f);
    int slot = slotOf[rowBase + row];
    ndP[(size_t)slot * 64 + k] = -dist * TAUINV;
  }
}

// ---------------- device-wide barrier (136 co-resident blocks) ----------------
__device__ __forceinline__ void gbar(int* bar) {
  __syncthreads();
  if (threadIdx.x == 0) {
    __threadfence();
    int g = __hip_atomic_load(&bar[1], __ATOMIC_ACQUIRE, __HIP_MEMORY_SCOPE_AGENT);
    int a = __hip_atomic_fetch_add(&bar[0], 1, __ATOMIC_ACQ_REL, __HIP_MEMORY_SCOPE_AGENT);
    if (a == NSBLK - 1) {
      __hip_atomic_store(&bar[0], 0, __ATOMIC_RELAXED, __HIP_MEMORY_SCOPE_AGENT);
      __hip_atomic_fetch_add(&bar[1], 1, __ATOMIC_RELEASE, __HIP_MEMORY_SCOPE_AGENT);
    } else {
      while (__hip_atomic_load(&bar[1], __ATOMIC_ACQUIRE, __HIP_MEMORY_SCOPE_AGENT) == g)
        __builtin_amdgcn_s_sleep(2);
    }
  }
  __syncthreads();
}

// ---------------- persistent Sinkhorn ----------------
__global__ __launch_bounds__(512, 1) void k_sink(
    const float* __restrict__ ndP, const int* __restrict__ off,
    const float* __restrict__ dustc,
    unsigned long long* colp, unsigned long long* dustp,
    int* bar, float* lvF, float* logu)
{
  const int b = blockIdx.x;
  const int t = b / PB;
  const int p = b - t * PB;
  const int tid = threadIdx.x;
  const int lane = tid & 63;
  const int w = tid >> 6;

  const int o0 = off[t];
  const int nt = off[t + 1] - o0;
  const int chunk = (nt + PB - 1) / PB;
  const int s0 = o0 + p * chunk;
  int R = nt - p * chunk;
  R = R < 0 ? 0 : (R > chunk ? chunk : R);
  R = R > MAXR ? MAXR : R;

  const float dustArg = -fabsf(dustc[0]) * TAUINV;

  __shared__ float ndL[MAXR * 65];
  __shared__ float luL[MAXR];
  __shared__ float lvL[NPROTO];
  __shared__ float cmax[NPROTO];
  __shared__ float skw[8 * NPROTO];
  __shared__ float wred[8];
  __shared__ float s_lvD;

  for (int idx = tid; idx < R * 64; idx += 512) {
    int r = idx >> 6, k = idx & 63;
    ndL[r * 65 + k] = ndP[(size_t)s0 * 64 + idx];
  }
  __syncthreads();

  { // per-column max of ndL (one-time)
    float m = -1e30f;
    for (int r = w; r < R; r += 8) m = fmaxf(m, ndL[r * 65 + lane]);
    skw[w * 64 + lane] = m;
  }
  __syncthreads();
  if (tid < 64) {
    float m = skw[tid];
    for (int c = 1; c < 8; ++c) m = fmaxf(m, skw[c * 64 + tid]);
    cmax[tid] = m;
  }
  __syncthreads();

  float lu = 0.0f;
  const bool have = (tid < R);

  for (int it = 0; it < NITERS; ++it) {
    // -- combine previous partials into lv / lvD --
    if (it == 0) {
      if (tid < 64) lvL[tid] = 0.0f;
      if (tid == 64) s_lvD = 0.0f;
    } else {
      const int pr = (it - 1) & 1;
      if (tid < 64) {
        float M = -1e30f, S = 0.0f;
        for (int pp = 0; pp < PB; ++pp) {
          unsigned long long v = __hip_atomic_load(
              &colp[(((size_t)pr * NTYPES + t) * PB + pp) * 64 + tid],
              __ATOMIC_RELAXED, __HIP_MEMORY_SCOPE_AGENT);
          float m, s; unpackms(v, m, s);
          msmerge(M, S, m, s);
        }
        lvL[tid] = -(M + __logf(fmaxf(S, 1e-35f)));
      } else if (w == 1) {
        float M = -1e30f, S = 0.0f;
        for (int j = lane; j < NSBLK; j += 64) {
          unsigned long long v = __hip_atomic_load(
              &dustp[(size_t)pr * NSBLK + j],
              __ATOMIC_RELAXED, __HIP_MEMORY_SCOPE_AGENT);
          float m, s; unpackms(v, m, s);
          msmerge(M, S, m, s);
        }
        for (int o = 32; o; o >>= 1) {
          float om = __shfl_xor(M, o), os = __shfl_xor(S, o);
          msmerge(M, S, om, os);
        }
        if (lane == 0)
          s_lvD = LOGN - (dustArg + M + __logf(fmaxf(S, 1e-35f)));
      }
    }
    __syncthreads();

    // -- u-update (row lse) --
    if (have) {
      const float dterm = dustArg + s_lvD;
      const float* nd = &ndL[tid * 65];
      float m = dterm;
      #pragma unroll
      for (int k = 0; k < 64; ++k) m = fmaxf(m, nd[k] + lvL[k]);
      float s = __expf(dterm - m);
      #pragma unroll
      for (int k = 0; k < 64; ++k) s += __expf(nd[k] + lvL[k] - m);
      lu = -(m + __logf(s));
      luL[tid] = lu;
      if (it == NITERS - 1) logu[s0 + tid] = lu;
    }
    __syncthreads();

    // -- block dust partial (max + sumexp of lu) --
    float lm = have ? lu : -1e30f;
    for (int o = 32; o; o >>= 1) lm = fmaxf(lm, __shfl_xor(lm, o));
    if (lane == 0) wred[w] = lm;
    __syncthreads();
    float luMax = wred[0];
    for (int c = 1; c < 8; ++c) luMax = fmaxf(luMax, wred[c]);
    __syncthreads();
    float e = have ? __expf(lu - luMax) : 0.0f;
    for (int o = 32; o; o >>= 1) e += __shfl_xor(e, o);
    if (lane == 0) wred[w] = e;
    __syncthreads();
    if (tid == 0) {
      float sD = 0.0f;
      for (int c = 0; c < 8; ++c) sD += wred[c];
      __hip_atomic_store(&dustp[(size_t)(it & 1) * NSBLK + b], packms(luMax, sD),
                         __ATOMIC_RELAXED, __HIP_MEMORY_SCOPE_AGENT);
    }

    // -- column partial sums with safe shift (cmax + luMax >= every term) --
    {
      const float shift = cmax[lane] + luMax;
      float ss = 0.0f;
      for (int r = w; r < R; r += 8)
        ss += __expf(ndL[r * 65 + lane] + luL[r] - shift);
      skw[w * 64 + lane] = ss;
    }
    __syncthreads();
    if (tid < 64) {
      float S = 0.0f;
      for (int c = 0; c < 8; ++c) S += skw[c * 64 + tid];
      __hip_atomic_store(&colp[(((size_t)(it & 1) * NTYPES + t) * PB + p) * 64 + tid],
                         packms(cmax[tid] + luMax, S),
                         __ATOMIC_RELAXED, __HIP_MEMORY_SCOPE_AGENT);
    }

    gbar(bar);
  }

  // -- final combine: write lv for output kernel (partials parity = 1) --
  if (p == 0 && tid < 64) {
    float M = -1e30f, S = 0.0f;
    for (int pp = 0; pp < PB; ++pp) {
      unsigned long long v = __hip_atomic_load(
          &colp[(((size_t)1 * NTYPES + t) * PB + pp) * 64 + tid],
          __ATOMIC_RELAXED, __HIP_MEMORY_SCOPE_AGENT);
      float m, s; unpackms(v, m, s);
      msmerge(M, S, m, s);
    }
    lvF[t * 64 + tid] = -(M + __logf(fmaxf(S, 1e-35f)));
  }
  if (b == 0 && w == 1) {
    float M = -1e30f, S = 0.0f;
    for (int j = lane; j < NSBLK; j += 64) {
      unsigned long long v = __hip_atomic_load(
          &dustp[(size_t)1 * NSBLK + j],
          __ATOMIC_RELAXED, __HIP_MEMORY_SCOPE_AGENT);
      float m, s; unpackms(v, m, s);
      msmerge(M, S, m, s);
    }
    for (int o = 32; o; o >>= 1) {
      float om = __shfl_xor(M, o), os = __shfl_xor(S, o);
      msmerge(M, S, om, os);
    }
    if (lane == 0)
      lvF[NCOLS - 1] = LOGN - (dustArg + M + __logf(fmaxf(S, 1e-35f)));
  }
}

// ---------------- outputs: logits + full T rows ----------------
__global__ void k_out(const float* __restrict__ ndP, const float* __restrict__ logu,
                      const float* __restrict__ lvF, const int* __restrict__ perm,
                      const int* __restrict__ jt, const float* __restrict__ dustc,
                      float* __restrict__ out)
{
  const int lane = threadIdx.x & 63;
  const int gw = (blockIdx.x * blockDim.x + threadIdx.x) >> 6;
  const int nw = (gridDim.x * blockDim.x) >> 6;
  const float lvD = lvF[NCOLS - 1];
  const float dustArg = -fabsf(dustc[0]) * TAUINV;

  for (int slot = gw; slot < NROWS; slot += nw) {
    const int row = perm[slot];
    const int t = jt[row];
    const float lu = logu[slot];
    const float nd = ndP[(size_t)slot * 64 + lane];
    const float tv = __expf(nd + lu + lvF[t * 64 + lane]);   // person_mass[row][lane]
    out[(size_t)row * 64 + lane] = __logf(tv + 1e-8f);
    const size_t base = (size_t)NROWS * 64 + (size_t)row * NCOLS;
    int k = lane / 17;
    int r = lane - k * 17;
    int c = lane;
    #pragma unroll
    for (int j = 0; j < 17; ++j) {
      float sv = __shfl(tv, k);
      out[base + c] = (r == t) ? sv : 0.0f;
      c += 64;
      r += 13; k += 3;
      int ge = (r >= 17) ? 1 : 0;
      r -= ge * 17; k += ge;
    }
    if (lane == 0) out[base + 1088] = __expf(dustArg + lu + lvD);
  }
}

extern "C" void kernel_launch(void* const* d_in, const int* in_sizes, int n_in,
                              void* d_out, int out_size, void* d_ws, size_t ws_size,
                              hipStream_t stream) {
  const float* emb   = (const float*)d_in[0];
  const float* w1    = (const float*)d_in[1];
  const float* b1    = (const float*)d_in[2];
  const float* proto = (const float*)d_in[3];
  const float* dustc = (const float*)d_in[4];
  const int*   jt    = (const int*)d_in[5];

  char* ws = (char*)d_ws;
  int* cnt    = (int*)(ws + WS_CNT);
  int* off    = (int*)(ws + WS_OFF);
  int* bar    = (int*)(ws + WS_BAR);
  unsigned long long* colp  = (unsigned long long*)(ws + WS_COLP);
  unsigned long long* dustp = (unsigned long long*)(ws + WS_DUSTP);
  float* lvF   = (float*)(ws + WS_LVF);
  float* logu  = (float*)(ws + WS_LOGU);
  int* slotOf  = (int*)(ws + WS_SLOTOF);
  int* perm    = (int*)(ws + WS_PERM);
  float* ndP   = (float*)(ws + WS_NDP);
  float* out   = (float*)d_out;

  hipMemsetAsync(ws, 0, 512, stream);                       // counts + barrier
  k_hist<<<NROWS / 256, 256, 0, stream>>>(jt, cnt);
  k_scan<<<1, 64, 0, stream>>>(cnt, off);
  k_rank<<<NTYPES, 256, 0, stream>>>(jt, off, slotOf, perm);
  k_prep<<<NROWS / 64, 512, 0, stream>>>(emb, w1, b1, proto, slotOf, ndP);
  k_sink<<<NSBLK, 512, 0, stream>>>(ndP, off, dustc, colp, dustp, bar, lvF, logu);
  k_out<<<2048, 256, 0, stream>>>(ndP, logu, lvF, perm, jt, dustc, out);
}

// Round 3
// 511.363 us; speedup vs baseline: 2.6141x; 2.6141x over previous
//
#include <hip/hip_runtime.h>
#include <cstdint>
#include <cstddef>

#define NROWS   32768
#define DIMD    256
#define NPROTO  64
#define NTYPES  17
#define NCOLS   1089          // 64*17 + 1
#define TAUINV  10.0f
#define NITERS  50
#define PB      8             // blocks per type
#define NSBLK   (NTYPES*PB)   // 136
#define MAXR    384
#define LOGN    10.397207708399179f   // ln(32768)
#define SELU_L  1.0507009873554805f
#define SELU_A  1.6732632423543772f

// ---- workspace byte offsets (identical to the proven round-1 layout) ----
#define WS_CNT     0          // int[17]
#define WS_OFF     128        // int[18]
#define WS_COLP    512        // ull[2][17][8][64] = 139264 B
#define WS_DUSTP   139776     // ull[2][136]       = 2176 B
#define WS_LVF     141952     // float[1089]
#define WS_LOGU    146432     // float[32768]
#define WS_SLOTOF  277504     // int[32768]
#define WS_PERM    408576     // int[32768]
#define WS_NDP     540672     // float[32768*64] = 8 MB -> end 8929280

// (m,s) packed in 64 bits; iteration tag lives in the low 8 mantissa bits of s
// (relative error <= 3e-5 on s, negligible after log()).
__device__ __forceinline__ unsigned long long packms_tag(float m, float s, unsigned tag) {
  unsigned su = (__float_as_uint(s) & ~0xFFu) | (tag & 0xFFu);
  return (unsigned long long)__float_as_uint(m) |
         ((unsigned long long)su << 32);
}
__device__ __forceinline__ void unpackms(unsigned long long v, float& m, float& s) {
  m = __uint_as_float((unsigned)(v & 0xffffffffu));
  s = __uint_as_float((unsigned)(v >> 32));
}
__device__ __forceinline__ bool tagok(unsigned long long v, unsigned tag) {
  return ((unsigned)(v >> 32) & 0xFFu) == tag;
}
// merge running (M,S) lse pair with (m,s)
__device__ __forceinline__ void msmerge(float& M, float& S, float m, float s) {
  if (m > M) { S = S * __expf(M - m) + s; M = m; }
  else       { S += s * __expf(m - M); }
}

// batched poll of the PB column-partial slots (stride 64) for one column
__device__ __forceinline__ void poll8t(const unsigned long long* base, unsigned tag,
                                       unsigned long long v[PB]) {
  for (;;) {
    bool ok = true;
    #pragma unroll
    for (int pp = 0; pp < PB; ++pp)
      v[pp] = __hip_atomic_load(base + (size_t)pp * 64,
                                __ATOMIC_RELAXED, __HIP_MEMORY_SCOPE_AGENT);
    #pragma unroll
    for (int pp = 0; pp < PB; ++pp)
      ok &= tagok(v[pp], tag);
    if (ok) return;
    __builtin_amdgcn_s_sleep(1);
  }
}

// poll+merge the 136 dust partials of one iteration across a 64-lane wave
__device__ __forceinline__ void polldust(const unsigned long long* d, unsigned tag,
                                         int lane, float& M, float& S) {
  const bool hasC = (lane + 128 < NSBLK);
  unsigned long long a, b2, c = 0ull;
  for (;;) {
    a  = __hip_atomic_load(d + lane,      __ATOMIC_RELAXED, __HIP_MEMORY_SCOPE_AGENT);
    b2 = __hip_atomic_load(d + lane + 64, __ATOMIC_RELAXED, __HIP_MEMORY_SCOPE_AGENT);
    if (hasC)
      c = __hip_atomic_load(d + lane + 128, __ATOMIC_RELAXED, __HIP_MEMORY_SCOPE_AGENT);
    bool ok = tagok(a, tag) && tagok(b2, tag) && (!hasC || tagok(c, tag));
    if (ok) break;
    __builtin_amdgcn_s_sleep(1);
  }
  M = -1e30f; S = 0.0f;
  float m, s;
  unpackms(a, m, s);  msmerge(M, S, m, s);
  unpackms(b2, m, s); msmerge(M, S, m, s);
  if (hasC) { unpackms(c, m, s); msmerge(M, S, m, s); }
  for (int o = 32; o; o >>= 1) {
    float om = __shfl_xor(M, o), os = __shfl_xor(S, o);
    msmerge(M, S, om, os);
  }
}

// ---------------- histogram of joint types ----------------
__global__ void k_hist(const int* __restrict__ jt, int* cnt) {
  int i = blockIdx.x * 256 + threadIdx.x;
  atomicAdd(&cnt[jt[i]], 1);
}

// ---------------- prefix over 17 counts ----------------
__global__ void k_scan(const int* __restrict__ cnt, int* off) {
  if (threadIdx.x == 0) {
    int run = 0;
    for (int t = 0; t < NTYPES; ++t) { off[t] = run; run += cnt[t]; }
    off[NTYPES] = run;
  }
}

// ---------------- deterministic per-type rank / permutation ----------------
__global__ __launch_bounds__(1024) void k_rank(const int* __restrict__ jt,
                                               const int* __restrict__ off,
                                               int* slotOf, int* perm) {
  const int t = blockIdx.x;
  const int tid = threadIdx.x;               // 1024
  const int lane = tid & 63, w = tid >> 6;   // 16 waves
  __shared__ int wtot[16];
  int running = 0;
  for (int base = 0; base < NROWS; base += 1024) {
    int i = base + tid;
    bool f = (jt[i] == t);
    unsigned long long mask = __ballot(f);
    int prefix = __popcll(mask & ((1ull << lane) - 1ull));
    int wcount = __popcll(mask);
    if (lane == 0) wtot[w] = wcount;
    __syncthreads();
    int woff = 0, btot = 0;
    for (int ww = 0; ww < 16; ++ww) {
      woff += (ww < w) ? wtot[ww] : 0;
      btot += wtot[ww];
    }
    if (f) {
      int slot = off[t] + running + woff + prefix;
      slotOf[i] = slot;
      perm[slot] = i;
    }
    running += btot;
    __syncthreads();
  }
}

// ---------------- fused  h = selu(emb@W1+b1);  negdist -> permuted slots ----------------
__global__ __launch_bounds__(512, 1) void k_prep(
    const float* __restrict__ emb, const float* __restrict__ w1,
    const float* __restrict__ b1,  const float* __restrict__ proto,
    const int* __restrict__ slotOf, float* __restrict__ ndP)
{
  __shared__ float EH[64 * 260];   // emb tile, later overwritten with h tile
  __shared__ float PT[256 * 65];   // protoT[d][k]
  __shared__ float hh[64];
  const int tid = threadIdx.x;
  const int rowBase = blockIdx.x * 64;

  for (int idx = tid; idx < 64 * 256; idx += 512) {
    int r = idx >> 8, d = idx & 255;
    EH[r * 260 + d] = emb[(size_t)(rowBase + r) * 256 + d];
  }
  for (int idx = tid; idx < 64 * 256; idx += 512) {
    int k = idx >> 8, d = idx & 255;
    PT[d * 65 + k] = proto[idx];
  }
  __syncthreads();

  const int jj = tid & 63;
  const int rr = tid >> 6;   // 0..7

  float acc[8][4];
  #pragma unroll
  for (int m = 0; m < 8; ++m)
    #pragma unroll
    for (int c = 0; c < 4; ++c) acc[m][c] = 0.0f;
  float bb[4];
  #pragma unroll
  for (int c = 0; c < 4; ++c) bb[c] = b1[jj + 64 * c];

  for (int k4 = 0; k4 < 256; k4 += 4) {
    float4 ev[8];
    #pragma unroll
    for (int m = 0; m < 8; ++m)
      ev[m] = *(const float4*)&EH[(rr * 8 + m) * 260 + k4];
    #pragma unroll
    for (int kk = 0; kk < 4; ++kk) {
      float wv[4];
      #pragma unroll
      for (int c = 0; c < 4; ++c)
        wv[c] = w1[(size_t)(k4 + kk) * 256 + jj + 64 * c];
      #pragma unroll
      for (int m = 0; m < 8; ++m) {
        float e = (kk == 0) ? ev[m].x : (kk == 1) ? ev[m].y : (kk == 2) ? ev[m].z : ev[m].w;
        #pragma unroll
        for (int c = 0; c < 4; ++c) acc[m][c] += e * wv[c];
      }
    }
  }

  float hv[8][4];
  float hs[8];
  #pragma unroll
  for (int m = 0; m < 8; ++m) {
    hs[m] = 0.0f;
    #pragma unroll
    for (int c = 0; c < 4; ++c) {
      float g = acc[m][c] + bb[c];
      float h = (g > 0.0f) ? SELU_L * g : SELU_L * SELU_A * (__expf(g) - 1.0f);
      hv[m][c] = h;
      hs[m] += h * h;
    }
  }
  __syncthreads();   // all reads of emb tile complete
  #pragma unroll
  for (int m = 0; m < 8; ++m)
    #pragma unroll
    for (int c = 0; c < 4; ++c)
      EH[(rr * 8 + m) * 260 + jj + 64 * c] = hv[m][c];
  #pragma unroll
  for (int m = 0; m < 8; ++m) {
    float v = hs[m];
    for (int o = 32; o; o >>= 1) v += __shfl_xor(v, o);
    if (jj == 0) hh[rr * 8 + m] = v;
  }
  __syncthreads();

  // phase B: dist against 64 prototypes
  const int k = jj;
  float da[8];
  #pragma unroll
  for (int m = 0; m < 8; ++m) da[m] = 0.0f;
  float pp = 0.0f;
  for (int d4 = 0; d4 < 256; d4 += 4) {
    float pv[4];
    #pragma unroll
    for (int dd = 0; dd < 4; ++dd) {
      float v = PT[(d4 + dd) * 65 + k];
      pv[dd] = v; pp += v * v;
    }
    #pragma unroll
    for (int m = 0; m < 8; ++m) {
      float4 h4 = *(const float4*)&EH[(rr * 8 + m) * 260 + d4];
      da[m] += h4.x * pv[0] + h4.y * pv[1] + h4.z * pv[2] + h4.w * pv[3];
    }
  }
  #pragma unroll
  for (int m = 0; m < 8; ++m) {
    int row = rr * 8 + m;
    float dist = hh[row] + pp - 2.0f * da[m];
    dist = fmaxf(dist, 0.0f);
    int slot = slotOf[rowBase + row];
    ndP[(size_t)slot * 64 + k] = -dist * TAUINV;
  }
}

// ---------------- persistent Sinkhorn, fence-free tagged dataflow ----------------
__global__ __launch_bounds__(512, 1) void k_sink(
    const float* __restrict__ ndP, const int* __restrict__ off,
    const float* __restrict__ dustc,
    unsigned long long* colp, unsigned long long* dustp,
    float* lvF, float* logu)
{
  const int b = blockIdx.x;
  const int t = b / PB;
  const int p = b - t * PB;
  const int tid = threadIdx.x;
  const int lane = tid & 63;
  const int w = tid >> 6;

  const int o0 = off[t];
  const int nt = off[t + 1] - o0;
  const int chunk = (nt + PB - 1) / PB;
  const int s0 = o0 + p * chunk;
  int R = nt - p * chunk;
  R = R < 0 ? 0 : (R > chunk ? chunk : R);
  R = R > MAXR ? MAXR : R;

  const float dustArg = -fabsf(dustc[0]) * TAUINV;

  __shared__ float ndL[MAXR * 65];
  __shared__ float luL[MAXR];
  __shared__ float lvL[NPROTO];
  __shared__ float cmax[NPROTO];
  __shared__ float skw[8 * NPROTO];
  __shared__ float wred[8];
  __shared__ float s_lvD;

  for (int idx = tid; idx < R * 64; idx += 512) {
    int r = idx >> 6, k = idx & 63;
    ndL[r * 65 + k] = ndP[(size_t)s0 * 64 + idx];
  }
  __syncthreads();

  { // per-column max of ndL (one-time)
    float m = -1e30f;
    for (int r = w; r < R; r += 8) m = fmaxf(m, ndL[r * 65 + lane]);
    skw[w * 64 + lane] = m;
  }
  __syncthreads();
  if (tid < 64) {
    float m = skw[tid];
    for (int c = 1; c < 8; ++c) m = fmaxf(m, skw[c * 64 + tid]);
    cmax[tid] = m;
  }
  __syncthreads();

  float lu = 0.0f;
  const bool have = (tid < R);

  for (int it = 0; it < NITERS; ++it) {
    // -- combine previous iteration's partials into lv / lvD (tagged poll) --
    if (it == 0) {
      if (tid < 64) lvL[tid] = 0.0f;
      if (tid == 64) s_lvD = 0.0f;
    } else {
      const unsigned tag = (unsigned)(it - 1) & 0xFFu;
      const int pr = (it - 1) & 1;
      if (tid < 64) {
        unsigned long long v[PB];
        poll8t(&colp[(((size_t)pr * NTYPES + t) * PB) * 64 + tid], tag, v);
        float M = -1e30f, S = 0.0f;
        #pragma unroll
        for (int pp = 0; pp < PB; ++pp) {
          float m, s; unpackms(v[pp], m, s);
          msmerge(M, S, m, s);
        }
        lvL[tid] = -(M + __logf(fmaxf(S, 1e-35f)));
      } else if (w == 1) {
        float M, S;
        polldust(&dustp[(size_t)pr * NSBLK], tag, lane, M, S);
        if (lane == 0)
          s_lvD = LOGN - (dustArg + M + __logf(fmaxf(S, 1e-35f)));
      }
    }
    __syncthreads();

    // -- u-update (row lse) --
    if (have) {
      const float dterm = dustArg + s_lvD;
      const float* nd = &ndL[tid * 65];
      float m = dterm;
      #pragma unroll
      for (int k = 0; k < 64; ++k) m = fmaxf(m, nd[k] + lvL[k]);
      float s = __expf(dterm - m);
      #pragma unroll
      for (int k = 0; k < 64; ++k) s += __expf(nd[k] + lvL[k] - m);
      lu = -(m + __logf(s));
      luL[tid] = lu;
      if (it == NITERS - 1) logu[s0 + tid] = lu;
    }
    __syncthreads();

    // -- block dust partial (max + sumexp of lu) --
    float lm = have ? lu : -1e30f;
    for (int o = 32; o; o >>= 1) lm = fmaxf(lm, __shfl_xor(lm, o));
    if (lane == 0) wred[w] = lm;
    __syncthreads();
    float luMax = wred[0];
    for (int c = 1; c < 8; ++c) luMax = fmaxf(luMax, wred[c]);
    __syncthreads();
    float e = have ? __expf(lu - luMax) : 0.0f;
    for (int o = 32; o; o >>= 1) e += __shfl_xor(e, o);
    if (lane == 0) wred[w] = e;
    __syncthreads();
    if (tid == 0) {
      float sD = 0.0f;
      for (int c = 0; c < 8; ++c) sD += wred[c];
      __hip_atomic_store(&dustp[(size_t)(it & 1) * NSBLK + b],
                         packms_tag(luMax, sD, (unsigned)it),
                         __ATOMIC_RELAXED, __HIP_MEMORY_SCOPE_AGENT);
    }

    // -- column partial sums with safe shift (cmax + luMax >= every term) --
    {
      const float shift = cmax[lane] + luMax;
      float ss = 0.0f;
      for (int r = w; r < R; r += 8)
        ss += __expf(ndL[r * 65 + lane] + luL[r] - shift);
      skw[w * 64 + lane] = ss;
    }
    __syncthreads();
    if (tid < 64) {
      float S = 0.0f;
      for (int c = 0; c < 8; ++c) S += skw[c * 64 + tid];
      __hip_atomic_store(&colp[(((size_t)(it & 1) * NTYPES + t) * PB + p) * 64 + tid],
                         packms_tag(cmax[tid] + luMax, S, (unsigned)it),
                         __ATOMIC_RELAXED, __HIP_MEMORY_SCOPE_AGENT);
    }
    // no global barrier: tagged polls provide ordering; slot reuse at distance 2
    // is safe because a writer reaches iteration it only after every block's
    // dust partial of it-1 is visible, which each block writes only after it
    // finished consuming the tag it-2 data being overwritten.
  }

  // -- final combine: write lv for output kernel (iteration NITERS-1, parity 1) --
  if (p == 0 && tid < 64) {
    unsigned long long v[PB];
    poll8t(&colp[(((size_t)((NITERS - 1) & 1) * NTYPES + t) * PB) * 64 + tid],
           (unsigned)(NITERS - 1) & 0xFFu, v);
    float M = -1e30f, S = 0.0f;
    #pragma unroll
    for (int pp = 0; pp < PB; ++pp) {
      float m, s; unpackms(v[pp], m, s);
      msmerge(M, S, m, s);
    }
    lvF[t * 64 + tid] = -(M + __logf(fmaxf(S, 1e-35f)));
  }
  if (b == 0 && w == 1) {
    float M, S;
    polldust(&dustp[(size_t)((NITERS - 1) & 1) * NSBLK],
             (unsigned)(NITERS - 1) & 0xFFu, lane, M, S);
    if (lane == 0)
      lvF[NCOLS - 1] = LOGN - (dustArg + M + __logf(fmaxf(S, 1e-35f)));
  }
}

// ---------------- outputs: logits + full T rows ----------------
__global__ void k_out(const float* __restrict__ ndP, const float* __restrict__ logu,
                      const float* __restrict__ lvF, const int* __restrict__ perm,
                      const int* __restrict__ jt, const float* __restrict__ dustc,
                      float* __restrict__ out)
{
  const int lane = threadIdx.x & 63;
  const int gw = (blockIdx.x * blockDim.x + threadIdx.x) >> 6;
  const int nw = (gridDim.x * blockDim.x) >> 6;
  const float lvD = lvF[NCOLS - 1];
  const float dustArg = -fabsf(dustc[0]) * TAUINV;

  for (int slot = gw; slot < NROWS; slot += nw) {
    const int row = perm[slot];
    const int t = jt[row];
    const float lu = logu[slot];
    const float nd = ndP[(size_t)slot * 64 + lane];
    const float tv = __expf(nd + lu + lvF[t * 64 + lane]);   // person_mass[row][lane]
    out[(size_t)row * 64 + lane] = __logf(tv + 1e-8f);
    const size_t base = (size_t)NROWS * 64 + (size_t)row * NCOLS;
    int k = lane / 17;
    int r = lane - k * 17;
    int c = lane;
    #pragma unroll
    for (int j = 0; j < 17; ++j) {
      float sv = __shfl(tv, k);
      out[base + c] = (r == t) ? sv : 0.0f;
      c += 64;
      r += 13; k += 3;
      int ge = (r >= 17) ? 1 : 0;
      r -= ge * 17; k += ge;
    }
    if (lane == 0) out[base + 1088] = __expf(dustArg + lu + lvD);
  }
}

extern "C" void kernel_launch(void* const* d_in, const int* in_sizes, int n_in,
                              void* d_out, int out_size, void* d_ws, size_t ws_size,
                              hipStream_t stream) {
  const float* emb   = (const float*)d_in[0];
  const float* w1    = (const float*)d_in[1];
  const float* b1    = (const float*)d_in[2];
  const float* proto = (const float*)d_in[3];
  const float* dustc = (const float*)d_in[4];
  const int*   jt    = (const int*)d_in[5];

  char* ws = (char*)d_ws;
  int* cnt    = (int*)(ws + WS_CNT);
  int* off    = (int*)(ws + WS_OFF);
  unsigned long long* colp  = (unsigned long long*)(ws + WS_COLP);
  unsigned long long* dustp = (unsigned long long*)(ws + WS_DUSTP);
  float* lvF   = (float*)(ws + WS_LVF);
  float* logu  = (float*)(ws + WS_LOGU);
  int* slotOf  = (int*)(ws + WS_SLOTOF);
  int* perm    = (int*)(ws + WS_PERM);
  float* ndP   = (float*)(ws + WS_NDP);
  float* out   = (float*)d_out;

  hipMemsetAsync(ws, 0, 512, stream);                         // counts
  hipMemsetAsync(ws + WS_COLP, 0xFF, 139264 + 2176, stream);  // tag sentinels (0xFF != any tag 0..49)
  k_hist<<<NROWS / 256, 256, 0, stream>>>(jt, cnt);
  k_scan<<<1, 64, 0, stream>>>(cnt, off);
  k_rank<<<NTYPES, 1024, 0, stream>>>(jt, off, slotOf, perm);
  k_prep<<<NROWS / 64, 512, 0, stream>>>(emb, w1, b1, proto, slotOf, ndP);
  k_sink<<<NSBLK, 512, 0, stream>>>(ndP, off, dustc, colp, dustp, lvF, logu);
  k_out<<<2048, 256, 0, stream>>>(ndP, logu, lvF, perm, jt, dustc, out);
}